// Round 3
// baseline (179.835 us; speedup 1.0000x reference)
//
#include <hip/hip_runtime.h>
#include <cstdint>
#include <cstddef>

#define BB 512
#define NEn 100000
#define NRr 400
#define AA 256
#define ENTd 200
#define RELd 200
#define HISTd 400
#define ADIMd 400

__device__ __forceinline__ float dot4(const float4 a, const float4 b) {
  return a.x * b.x + a.y * b.y + a.z * b.z + a.w * b.w;
}
__device__ __forceinline__ float wave_rmax(float v) {
#pragma unroll
  for (int off = 32; off > 0; off >>= 1) v = fmaxf(v, __shfl_xor(v, off));
  return v;
}
__device__ __forceinline__ float wave_rsum(float v) {
#pragma unroll
  for (int off = 32; off > 0; off >>= 1) v += __shfl_xor(v, off);
  return v;
}

// ---------------------------------------------------------------------------
// prep1: batch-invariant stage 1.
//  blk 0        : rel_sum -> ab = W5l.rel_sum + b5           [200]
//  blk 1..50    : RK = W4.rel + b4                           [400,200] (8 rows)
//  blk 51..75   : P = 400 * W6a . W5r                        [200,200] (8 rows)
//  blk 76..100  : W6bb = Watt_b . W6b                        [200,200] (8 rows)
// ---------------------------------------------------------------------------
__global__ __launch_bounds__(256) void prep1_kernel(
    const float* __restrict__ rel_emb, const float* __restrict__ W4,
    const float* __restrict__ b4, const float* __restrict__ W5,
    const float* __restrict__ b5, const float* __restrict__ W6,
    const float* __restrict__ Watt, float* __restrict__ RK,
    float* __restrict__ P, float* __restrict__ W6bb, float* __restrict__ ab) {
  int t = threadIdx.x;
  int blk = blockIdx.x;
  if (blk == 0) {
    __shared__ float rs[RELd];
    if (t < RELd) {
      float s = 0.f;
      for (int r = 0; r < NRr; ++r) s += rel_emb[(size_t)r * RELd + t];
      rs[t] = s;
    }
    __syncthreads();
    if (t < RELd) {
      float acc = b5[t];
      const float4* w = (const float4*)(W5 + (size_t)t * 400);
      for (int k = 0; k < 50; ++k) acc += dot4(w[k], ((const float4*)rs)[k]);
      ab[t] = acc;
    }
  } else if (blk <= 50) {
    int r0 = (blk - 1) * 8;
    __shared__ float re[8][RELd];
    for (int i = t; i < 8 * RELd; i += 256)
      re[i / RELd][i % RELd] = rel_emb[(size_t)(r0 + i / RELd) * RELd + i % RELd];
    __syncthreads();
    if (t < RELd) {
      float bv = b4[t];
      float acc[8];
#pragma unroll
      for (int s = 0; s < 8; ++s) acc[s] = bv;
      const float4* w = (const float4*)(W4 + (size_t)t * RELd);
      for (int k = 0; k < RELd / 4; ++k) {
        float4 wv = w[k];
#pragma unroll
        for (int s = 0; s < 8; ++s) acc[s] += dot4(wv, ((const float4*)re[s])[k]);
      }
#pragma unroll
      for (int s = 0; s < 8; ++s) RK[(size_t)(r0 + s) * RELd + t] = acc[s];
    }
  } else if (blk <= 75) {
    int i0 = (blk - 51) * 8;
    __shared__ float w6s[8][200];
    for (int i = t; i < 8 * 200; i += 256)
      w6s[i / 200][i % 200] = W6[(size_t)(i0 + i / 200) * 400 + i % 200];
    __syncthreads();
    if (t < 200) {
      int k = t;
      float acc[8] = {0, 0, 0, 0, 0, 0, 0, 0};
      for (int j = 0; j < 200; ++j) {
        float rd = W5[(size_t)j * 400 + 200 + k];
#pragma unroll
        for (int s = 0; s < 8; ++s) acc[s] += w6s[s][j] * rd;
      }
#pragma unroll
      for (int s = 0; s < 8; ++s) P[(size_t)(i0 + s) * 200 + k] = 400.f * acc[s];
    }
  } else {
    int u0 = (blk - 76) * 8;
    __shared__ float wbs[8][200];
    for (int i = t; i < 8 * 200; i += 256)
      wbs[i / 200][i % 200] = Watt[(size_t)(u0 + i / 200) * 600 + 400 + i % 200];
    __syncthreads();
    if (t < 200) {
      int j = t;
      float acc[8] = {0, 0, 0, 0, 0, 0, 0, 0};
      for (int i = 0; i < 200; ++i) {
        float rd = W6[(size_t)i * 400 + 200 + j];
#pragma unroll
        for (int s = 0; s < 8; ++s) acc[s] += wbs[s][i] * rd;
      }
#pragma unroll
      for (int s = 0; s < 8; ++s) W6bb[(size_t)(u0 + s) * 200 + j] = acc[s];
    }
  }
}

// ---------------------------------------------------------------------------
// prep2: batch-invariant stage 2.
//  blk 0..49   : S_r = W3^T . RK_r ; c_r = b3.RK_r (8 rows)
//  blk 50..74  : Q = Watt_b . P    (8 rows)
//  blk 75..124 : REatt_T[j][r] = rel_r . W6bb_j  (8 r's, transposed store)
//  blk 125     : v1 = batt + Watt_b.(b6 + W6a.ab)
// ---------------------------------------------------------------------------
__global__ __launch_bounds__(256) void prep2_kernel(
    const float* __restrict__ rel_emb, const float* __restrict__ W3,
    const float* __restrict__ b3, const float* __restrict__ W6,
    const float* __restrict__ Watt, const float* __restrict__ batt,
    const float* __restrict__ b6, const float* __restrict__ RK,
    const float* __restrict__ P, const float* __restrict__ W6bb,
    const float* __restrict__ ab, float* __restrict__ S,
    float* __restrict__ cvec, float* __restrict__ Q,
    float* __restrict__ REatt_T, float* __restrict__ v1) {
  int t = threadIdx.x;
  int blk = blockIdx.x;
  if (blk < 50) {
    int r0 = blk * 8;
    __shared__ float rks[8][200];
    __shared__ float b3s[200];
    for (int i = t; i < 8 * 200; i += 256)
      rks[i / 200][i % 200] = RK[(size_t)(r0 + i / 200) * 200 + i % 200];
    if (t < 200) b3s[t] = b3[t];
    __syncthreads();
    if (t < 200) {
      int i = t;
      float acc[8] = {0, 0, 0, 0, 0, 0, 0, 0};
      for (int j = 0; j < 200; ++j) {
        float w3v = W3[(size_t)j * 200 + i];
#pragma unroll
        for (int s = 0; s < 8; ++s) acc[s] += w3v * rks[s][j];
      }
#pragma unroll
      for (int s = 0; s < 8; ++s) S[(size_t)(r0 + s) * 200 + i] = acc[s];
    }
    {
      int w = t >> 6, lane = t & 63;
      float p0 = 0.f, p1 = 0.f;
      for (int j = lane; j < 200; j += 64) {
        p0 += b3s[j] * rks[w][j];
        p1 += b3s[j] * rks[w + 4][j];
      }
      p0 = wave_rsum(p0);
      p1 = wave_rsum(p1);
      if (lane == 0) {
        cvec[r0 + w] = p0;
        cvec[r0 + w + 4] = p1;
      }
    }
  } else if (blk < 75) {
    int u0 = (blk - 50) * 8;
    __shared__ float wbs[8][200];
    for (int i = t; i < 8 * 200; i += 256)
      wbs[i / 200][i % 200] = Watt[(size_t)(u0 + i / 200) * 600 + 400 + i % 200];
    __syncthreads();
    if (t < 200) {
      int k = t;
      float acc[8] = {0, 0, 0, 0, 0, 0, 0, 0};
      for (int i = 0; i < 200; ++i) {
        float rd = P[(size_t)i * 200 + k];
#pragma unroll
        for (int s = 0; s < 8; ++s) acc[s] += wbs[s][i] * rd;
      }
#pragma unroll
      for (int s = 0; s < 8; ++s) Q[(size_t)(u0 + s) * 200 + k] = acc[s];
    }
  } else if (blk < 125) {
    int r0 = (blk - 75) * 8;
    __shared__ float rels[8][200];
    for (int i = t; i < 8 * 200; i += 256)
      rels[i / 200][i % 200] = rel_emb[(size_t)(r0 + i / 200) * 200 + i % 200];
    __syncthreads();
    if (t < 200) {
      float acc[8] = {0, 0, 0, 0, 0, 0, 0, 0};
      const float4* w = (const float4*)(W6bb + (size_t)t * 200);
      for (int k = 0; k < 50; ++k) {
        float4 wv = w[k];
#pragma unroll
        for (int s = 0; s < 8; ++s) acc[s] += dot4(wv, ((const float4*)rels[s])[k]);
      }
      // transposed store: REatt_T[j][r]
#pragma unroll
      for (int s = 0; s < 8; ++s) REatt_T[(size_t)t * 400 + r0 + s] = acc[s];
    }
  } else {
    __shared__ float abs_[200];
    __shared__ float us[200];
    if (t < 200) abs_[t] = ab[t];
    __syncthreads();
    if (t < 200) {
      float u = b6[t];
      const float4* w = (const float4*)(W6 + (size_t)t * 400);
      for (int k = 0; k < 50; ++k) u += dot4(w[k], ((const float4*)abs_)[k]);
      us[t] = u;
    }
    __syncthreads();
    if (t < 200) {
      float v = batt[t];
      const float4* w = (const float4*)(Watt + (size_t)t * 600 + 400);
      for (int k = 0; k < 50; ++k) v += dot4(w[k], ((const float4*)us)[k]);
      v1[t] = v;
    }
  }
}

// ---------------------------------------------------------------------------
// x1: X = relu(W1 . cat(E,H,Q) + b1)
// grid (128, 8): 4 batch rows x 50-output tile; 4-way k-split (chains 50 f4)
// ---------------------------------------------------------------------------
__global__ __launch_bounds__(256) void x1_kernel(
    const float* __restrict__ ent_emb, const float* __restrict__ rel_emb,
    const float* __restrict__ H, const int* __restrict__ e_idx,
    const int* __restrict__ q_idx, const float* __restrict__ W1,
    const float* __restrict__ b1, float* __restrict__ X) {
  int b0 = blockIdx.x * 4;
  int j0 = blockIdx.y * 50;
  int t = threadIdx.x;
  __shared__ float cv[4][800];
  __shared__ float part[4][50][4];  // [kq][j][s]
  for (int i = t; i < 4 * 800; i += 256) {
    int s = i / 800, k = i % 800;
    float v;
    if (k < ENTd)
      v = ent_emb[(size_t)e_idx[b0 + s] * ENTd + k];
    else if (k < ENTd + HISTd)
      v = H[(size_t)(b0 + s) * HISTd + (k - ENTd)];
    else
      v = rel_emb[(size_t)q_idx[b0 + s] * RELd + (k - ENTd - HISTd)];
    cv[s][k] = v;
  }
  __syncthreads();
  if (t < 200) {
    int j = t % 50, kq = t / 50;
    const float4* w = (const float4*)(W1 + (size_t)(j0 + j) * 800 + kq * 200);
    float acc[4] = {0, 0, 0, 0};
    for (int k = 0; k < 50; ++k) {
      float4 wv = w[k];
#pragma unroll
      for (int s = 0; s < 4; ++s)
        acc[s] += dot4(wv, ((const float4*)cv[s])[kq * 50 + k]);
    }
#pragma unroll
    for (int s = 0; s < 4; ++s) part[kq][j][s] = acc[s];
  }
  __syncthreads();
  if (t < 50) {
    float bv = b1[j0 + t];
#pragma unroll
    for (int s = 0; s < 4; ++s)
      X[(size_t)(b0 + s) * ADIMd + j0 + t] =
          fmaxf(bv + part[0][t][s] + part[1][t][s] + part[2][t][s] +
                    part[3][t][s],
                0.f);
  }
}

// ---------------------------------------------------------------------------
// x2: X2 = W2 . X + b2   grid (128, 8): 4 rows x 50-out tile, 4-way k-split
// ---------------------------------------------------------------------------
__global__ __launch_bounds__(256) void x2_kernel(
    const float* __restrict__ X, const float* __restrict__ W2,
    const float* __restrict__ b2, float* __restrict__ X2) {
  int b0 = blockIdx.x * 4;
  int j0 = blockIdx.y * 50;
  int t = threadIdx.x;
  __shared__ float cv[4][400];
  __shared__ float part[4][50][4];
  for (int i = t; i < 4 * 400; i += 256)
    cv[i / 400][i % 400] = X[(size_t)b0 * 400 + i];
  __syncthreads();
  if (t < 200) {
    int j = t % 50, kq = t / 50;
    const float4* w = (const float4*)(W2 + (size_t)(j0 + j) * 400 + kq * 100);
    float acc[4] = {0, 0, 0, 0};
    for (int k = 0; k < 25; ++k) {
      float4 wv = w[k];
#pragma unroll
      for (int s = 0; s < 4; ++s)
        acc[s] += dot4(wv, ((const float4*)cv[s])[kq * 25 + k]);
    }
#pragma unroll
    for (int s = 0; s < 4; ++s) part[kq][j][s] = acc[s];
  }
  __syncthreads();
  if (t < 50) {
    float bv = b2[j0 + t];
#pragma unroll
    for (int s = 0; s < 4; ++s)
      X2[(size_t)(b0 + s) * ADIMd + j0 + t] =
          bv + part[0][t][s] + part[1][t][s] + part[2][t][s] + part[3][t][s];
  }
}

// ---------------------------------------------------------------------------
// fused_mid: ONE batch row per block (512 blocks x 512 threads):
//   la = S.pe + c ; p = softmax(la) ;
//   attv = Watt_a.X2 + Q.pe + REatt_T.p + v1  (2-thread k-split) ;
//   ratt = softmax(rel . attv) -> out
// ---------------------------------------------------------------------------
__global__ __launch_bounds__(512) void fused_mid_kernel(
    const float* __restrict__ ent_emb, const float* __restrict__ rel_emb,
    const int* __restrict__ pred_id, const float* __restrict__ X2,
    const float* __restrict__ S, const float* __restrict__ cvec,
    const float* __restrict__ Q, const float* __restrict__ REatt_T,
    const float* __restrict__ v1, const float* __restrict__ Watt,
    float* __restrict__ out_ratt) {
  int b = blockIdx.x;
  int t = threadIdx.x;
  __shared__ float pe[200];
  __shared__ float x2s[400];
  __shared__ float pp[400];
  __shared__ float av[200];
  __shared__ float wred[8];
  if (t < 400) x2s[t] = X2[(size_t)b * 400 + t];
  if (t < 200) pe[t] = ent_emb[(size_t)pred_id[b] * ENTd + t];
  __syncthreads();
  // la
  if (t < 400) {
    float a = cvec[t];
    const float4* sp = (const float4*)(S + (size_t)t * 200);
    for (int k = 0; k < 50; ++k) a += dot4(sp[k], ((const float4*)pe)[k]);
    pp[t] = a;
  }
  __syncthreads();
  int w = t >> 6, lane = t & 63;
  // softmax(pp)
  {
    float v = (t < 400) ? pp[t] : -INFINITY;
    float m = wave_rmax(v);
    if (lane == 0) wred[w] = m;
    __syncthreads();
    float gm = wred[0];
#pragma unroll
    for (int i = 1; i < 8; ++i) gm = fmaxf(gm, wred[i]);
    __syncthreads();
    float e = (t < 400) ? expf(pp[t] - gm) : 0.f;
    float sw = wave_rsum(e);
    if (lane == 0) wred[w] = sw;
    __syncthreads();
    float gs = 0.f;
#pragma unroll
    for (int i = 0; i < 8; ++i) gs += wred[i];
    if (t < 400) pp[t] = e / gs;
  }
  __syncthreads();
  // attv, 2 threads per output j (h=0: Watt_a.x2 ; h=1: Q.pe + REatt_T.p)
  if (t < 400) {
    int j = t >> 1, h = t & 1;
    float a;
    if (h == 0) {
      a = v1[j];
      const float4* wp = (const float4*)(Watt + (size_t)j * 600);
      for (int k = 0; k < 100; ++k) a += dot4(wp[k], ((const float4*)x2s)[k]);
    } else {
      a = 0.f;
      const float4* qp = (const float4*)(Q + (size_t)j * 200);
      for (int k = 0; k < 50; ++k) a += dot4(qp[k], ((const float4*)pe)[k]);
      const float4* rp = (const float4*)(REatt_T + (size_t)j * 400);
      for (int k = 0; k < 100; ++k) a += dot4(rp[k], ((const float4*)pp)[k]);
    }
    a += __shfl_xor(a, 1);
    if (h == 0) av[j] = a;
  }
  __syncthreads();
  // logits
  float lg = -INFINITY;
  if (t < 400) {
    const float4* rp = (const float4*)(rel_emb + (size_t)t * 200);
    float l = 0.f;
    for (int k = 0; k < 50; ++k) l += dot4(rp[k], ((const float4*)av)[k]);
    lg = l;
  }
  __syncthreads();
  // softmax + write
  {
    float m = wave_rmax(lg);
    if (lane == 0) wred[w] = m;
    __syncthreads();
    float gm = wred[0];
#pragma unroll
    for (int i = 1; i < 8; ++i) gm = fmaxf(gm, wred[i]);
    __syncthreads();
    float e = (t < 400) ? expf(lg - gm) : 0.f;
    float sw = wave_rsum(e);
    if (lane == 0) wred[w] = sw;
    __syncthreads();
    float gs = 0.f;
#pragma unroll
    for (int i = 0; i < 8; ++i) gs += wred[i];
    if (t < 400) out_ratt[(size_t)b * 400 + t] = e / gs;
  }
}

// ---------------------------------------------------------------------------
// scores: one row per block, 512 threads, 2 threads per action (rel/ent halves)
// ---------------------------------------------------------------------------
__global__ __launch_bounds__(512) void scores_kernel(
    const float* __restrict__ X2, const float* __restrict__ rel_emb,
    const float* __restrict__ ent_emb, const int* __restrict__ r_space,
    const int* __restrict__ e_space, const float* __restrict__ mask,
    float* __restrict__ out_dist, float* __restrict__ out_ent) {
  int b = blockIdx.x;
  int t = threadIdx.x;
  __shared__ float x2s[400];
  __shared__ float wred[8];
  if (t < 400) x2s[t] = X2[(size_t)b * ADIMd + t];
  __syncthreads();
  int a = t >> 1, h = t & 1;
  float acc = 0.f;
  if (h == 0) {
    int r = r_space[(size_t)b * AA + a];
    const float4* rp = (const float4*)(rel_emb + (size_t)r * RELd);
    for (int k = 0; k < 50; ++k) acc += dot4(rp[k], ((const float4*)x2s)[k]);
  } else {
    int ei = e_space[(size_t)b * AA + a];
    const float4* ep = (const float4*)(ent_emb + (size_t)ei * ENTd);
    for (int k = 0; k < 50; ++k) acc += dot4(ep[k], ((const float4*)x2s)[50 + k]);
  }
  acc += __shfl_xor(acc, 1);  // both threads of pair hold full dot
  float score = acc - (1.f - mask[(size_t)b * AA + a]) * 1e31f;
  int w = t >> 6, lane = t & 63;
  float m = wave_rmax(score);
  if (lane == 0) wred[w] = m;
  __syncthreads();
  float gm = wred[0];
#pragma unroll
  for (int i = 1; i < 8; ++i) gm = fmaxf(gm, wred[i]);
  __syncthreads();
  float e = expf(score - gm);
  float sw = wave_rsum(e);  // each action counted twice
  if (lane == 0) wred[w] = sw;
  __syncthreads();
  float gs = 0.f;
#pragma unroll
  for (int i = 0; i < 8; ++i) gs += wred[i];
  gs *= 0.5f;
  float p = e / gs;
  if (h == 0) out_dist[(size_t)b * AA + a] = p;
  float entv = -p * logf(p + 1e-20f);
  float ew = wave_rsum(entv);  // counted twice
  __syncthreads();
  if (lane == 0) wred[w] = ew;
  __syncthreads();
  if (t == 0) {
    float s = 0.f;
#pragma unroll
    for (int i = 0; i < 8; ++i) s += wred[i];
    out_ent[b] = s * 0.5f;
  }
}

// ---------------------------------------------------------------------------
extern "C" void kernel_launch(void* const* d_in, const int* in_sizes, int n_in,
                              void* d_out, int out_size, void* d_ws,
                              size_t ws_size, hipStream_t stream) {
  const float* H = (const float*)d_in[0];
  const float* mask = (const float*)d_in[1];
  const float* ent_emb = (const float*)d_in[2];
  const float* rel_emb = (const float*)d_in[3];
  const float* W1 = (const float*)d_in[4];
  const float* b1 = (const float*)d_in[5];
  const float* W2 = (const float*)d_in[6];
  const float* b2 = (const float*)d_in[7];
  const float* W3 = (const float*)d_in[8];
  const float* b3 = (const float*)d_in[9];
  const float* W4 = (const float*)d_in[10];
  const float* b4 = (const float*)d_in[11];
  const float* W5 = (const float*)d_in[12];
  const float* b5 = (const float*)d_in[13];
  const float* W6 = (const float*)d_in[14];
  const float* b6 = (const float*)d_in[15];
  const float* Watt = (const float*)d_in[16];
  const float* batt = (const float*)d_in[17];
  const int* e_idx = (const int*)d_in[18];
  const int* q_idx = (const int*)d_in[19];
  const int* pred_id = (const int*)d_in[20];
  const int* r_space = (const int*)d_in[21];
  const int* e_space = (const int*)d_in[22];

  float* ws = (float*)d_ws;
  float* RK = ws;                  // 80000
  float* S = ws + 80000;           // 80000
  float* cvec = ws + 160000;       // 512
  float* P = ws + 160512;          // 40000
  float* Q = ws + 200512;          // 40000
  float* W6bb = ws + 240512;       // 40000
  float* REatt_T = ws + 280512;    // 80000 (transposed [200][400])
  float* ab = ws + 360512;         // 256
  float* v1 = ws + 360768;         // 256
  float* X = ws + 361024;          // 204800
  float* X2 = ws + 565824;         // 204800

  float* out = (float*)d_out;
  float* out_dist = out;                 // [512,256]
  float* out_ent = out + BB * AA;        // [512]
  float* out_ratt = out + BB * AA + BB;  // [512,400]

  hipLaunchKernelGGL(prep1_kernel, dim3(101), dim3(256), 0, stream, rel_emb,
                     W4, b4, W5, b5, W6, Watt, RK, P, W6bb, ab);
  hipLaunchKernelGGL(prep2_kernel, dim3(126), dim3(256), 0, stream, rel_emb,
                     W3, b3, W6, Watt, batt, b6, RK, P, W6bb, ab, S, cvec, Q,
                     REatt_T, v1);
  hipLaunchKernelGGL(x1_kernel, dim3(128, 8), dim3(256), 0, stream, ent_emb,
                     rel_emb, H, e_idx, q_idx, W1, b1, X);
  hipLaunchKernelGGL(x2_kernel, dim3(128, 8), dim3(256), 0, stream, X, W2, b2,
                     X2);
  hipLaunchKernelGGL(fused_mid_kernel, dim3(512), dim3(512), 0, stream,
                     ent_emb, rel_emb, pred_id, X2, S, cvec, Q, REatt_T, v1,
                     Watt, out_ratt);
  hipLaunchKernelGGL(scores_kernel, dim3(512), dim3(512), 0, stream, X2,
                     rel_emb, ent_emb, r_space, e_space, mask, out_dist,
                     out_ent);
}

// Round 4
// 166.168 us; speedup vs baseline: 1.0822x; 1.0822x over previous
//
#include <hip/hip_runtime.h>
#include <cstdint>
#include <cstddef>

#define BB 512
#define NEn 100000
#define NRr 400
#define AA 256
#define ENTd 200
#define RELd 200
#define HISTd 400
#define ADIMd 400

__device__ __forceinline__ float dot4(const float4 a, const float4 b) {
  return a.x * b.x + a.y * b.y + a.z * b.z + a.w * b.w;
}
__device__ __forceinline__ float wave_rmax(float v) {
#pragma unroll
  for (int off = 32; off > 0; off >>= 1) v = fmaxf(v, __shfl_xor(v, off));
  return v;
}
__device__ __forceinline__ float wave_rsum(float v) {
#pragma unroll
  for (int off = 32; off > 0; off >>= 1) v += __shfl_xor(v, off);
  return v;
}

// ---------------------------------------------------------------------------
// prep1: batch-invariant stage 1.
// ---------------------------------------------------------------------------
__global__ __launch_bounds__(256) void prep1_kernel(
    const float* __restrict__ rel_emb, const float* __restrict__ W4,
    const float* __restrict__ b4, const float* __restrict__ W5,
    const float* __restrict__ b5, const float* __restrict__ W6,
    const float* __restrict__ Watt, float* __restrict__ RK,
    float* __restrict__ P, float* __restrict__ W6bb, float* __restrict__ ab) {
  int t = threadIdx.x;
  int blk = blockIdx.x;
  if (blk == 0) {
    __shared__ float rs[RELd];
    if (t < RELd) {
      float s = 0.f;
      for (int r = 0; r < NRr; ++r) s += rel_emb[(size_t)r * RELd + t];
      rs[t] = s;
    }
    __syncthreads();
    if (t < RELd) {
      float acc = b5[t];
      const float4* w = (const float4*)(W5 + (size_t)t * 400);
      for (int k = 0; k < 50; ++k) acc += dot4(w[k], ((const float4*)rs)[k]);
      ab[t] = acc;
    }
  } else if (blk <= 50) {
    int r0 = (blk - 1) * 8;
    __shared__ float re[8][RELd];
    for (int i = t; i < 8 * RELd; i += 256)
      re[i / RELd][i % RELd] = rel_emb[(size_t)(r0 + i / RELd) * RELd + i % RELd];
    __syncthreads();
    if (t < RELd) {
      float bv = b4[t];
      float acc[8];
#pragma unroll
      for (int s = 0; s < 8; ++s) acc[s] = bv;
      const float4* w = (const float4*)(W4 + (size_t)t * RELd);
      for (int k = 0; k < RELd / 4; ++k) {
        float4 wv = w[k];
#pragma unroll
        for (int s = 0; s < 8; ++s) acc[s] += dot4(wv, ((const float4*)re[s])[k]);
      }
#pragma unroll
      for (int s = 0; s < 8; ++s) RK[(size_t)(r0 + s) * RELd + t] = acc[s];
    }
  } else if (blk <= 75) {
    int i0 = (blk - 51) * 8;
    __shared__ float w6s[8][200];
    for (int i = t; i < 8 * 200; i += 256)
      w6s[i / 200][i % 200] = W6[(size_t)(i0 + i / 200) * 400 + i % 200];
    __syncthreads();
    if (t < 200) {
      int k = t;
      float acc[8] = {0, 0, 0, 0, 0, 0, 0, 0};
      for (int j = 0; j < 200; ++j) {
        float rd = W5[(size_t)j * 400 + 200 + k];
#pragma unroll
        for (int s = 0; s < 8; ++s) acc[s] += w6s[s][j] * rd;
      }
#pragma unroll
      for (int s = 0; s < 8; ++s) P[(size_t)(i0 + s) * 200 + k] = 400.f * acc[s];
    }
  } else {
    int u0 = (blk - 76) * 8;
    __shared__ float wbs[8][200];
    for (int i = t; i < 8 * 200; i += 256)
      wbs[i / 200][i % 200] = Watt[(size_t)(u0 + i / 200) * 600 + 400 + i % 200];
    __syncthreads();
    if (t < 200) {
      int j = t;
      float acc[8] = {0, 0, 0, 0, 0, 0, 0, 0};
      for (int i = 0; i < 200; ++i) {
        float rd = W6[(size_t)i * 400 + 200 + j];
#pragma unroll
        for (int s = 0; s < 8; ++s) acc[s] += wbs[s][i] * rd;
      }
#pragma unroll
      for (int s = 0; s < 8; ++s) W6bb[(size_t)(u0 + s) * 200 + j] = acc[s];
    }
  }
}

// ---------------------------------------------------------------------------
// prep2: batch-invariant stage 2.
// ---------------------------------------------------------------------------
__global__ __launch_bounds__(256) void prep2_kernel(
    const float* __restrict__ rel_emb, const float* __restrict__ W3,
    const float* __restrict__ b3, const float* __restrict__ W6,
    const float* __restrict__ Watt, const float* __restrict__ batt,
    const float* __restrict__ b6, const float* __restrict__ RK,
    const float* __restrict__ P, const float* __restrict__ W6bb,
    const float* __restrict__ ab, float* __restrict__ S,
    float* __restrict__ cvec, float* __restrict__ Q,
    float* __restrict__ REatt_T, float* __restrict__ v1) {
  int t = threadIdx.x;
  int blk = blockIdx.x;
  if (blk < 50) {
    int r0 = blk * 8;
    __shared__ float rks[8][200];
    __shared__ float b3s[200];
    for (int i = t; i < 8 * 200; i += 256)
      rks[i / 200][i % 200] = RK[(size_t)(r0 + i / 200) * 200 + i % 200];
    if (t < 200) b3s[t] = b3[t];
    __syncthreads();
    if (t < 200) {
      int i = t;
      float acc[8] = {0, 0, 0, 0, 0, 0, 0, 0};
      for (int j = 0; j < 200; ++j) {
        float w3v = W3[(size_t)j * 200 + i];
#pragma unroll
        for (int s = 0; s < 8; ++s) acc[s] += w3v * rks[s][j];
      }
#pragma unroll
      for (int s = 0; s < 8; ++s) S[(size_t)(r0 + s) * 200 + i] = acc[s];
    }
    {
      int w = t >> 6, lane = t & 63;
      float p0 = 0.f, p1 = 0.f;
      for (int j = lane; j < 200; j += 64) {
        p0 += b3s[j] * rks[w][j];
        p1 += b3s[j] * rks[w + 4][j];
      }
      p0 = wave_rsum(p0);
      p1 = wave_rsum(p1);
      if (lane == 0) {
        cvec[r0 + w] = p0;
        cvec[r0 + w + 4] = p1;
      }
    }
  } else if (blk < 75) {
    int u0 = (blk - 50) * 8;
    __shared__ float wbs[8][200];
    for (int i = t; i < 8 * 200; i += 256)
      wbs[i / 200][i % 200] = Watt[(size_t)(u0 + i / 200) * 600 + 400 + i % 200];
    __syncthreads();
    if (t < 200) {
      int k = t;
      float acc[8] = {0, 0, 0, 0, 0, 0, 0, 0};
      for (int i = 0; i < 200; ++i) {
        float rd = P[(size_t)i * 200 + k];
#pragma unroll
        for (int s = 0; s < 8; ++s) acc[s] += wbs[s][i] * rd;
      }
#pragma unroll
      for (int s = 0; s < 8; ++s) Q[(size_t)(u0 + s) * 200 + k] = acc[s];
    }
  } else if (blk < 125) {
    int r0 = (blk - 75) * 8;
    __shared__ float rels[8][200];
    for (int i = t; i < 8 * 200; i += 256)
      rels[i / 200][i % 200] = rel_emb[(size_t)(r0 + i / 200) * 200 + i % 200];
    __syncthreads();
    if (t < 200) {
      float acc[8] = {0, 0, 0, 0, 0, 0, 0, 0};
      const float4* w = (const float4*)(W6bb + (size_t)t * 200);
      for (int k = 0; k < 50; ++k) {
        float4 wv = w[k];
#pragma unroll
        for (int s = 0; s < 8; ++s) acc[s] += dot4(wv, ((const float4*)rels[s])[k]);
      }
#pragma unroll
      for (int s = 0; s < 8; ++s) REatt_T[(size_t)t * 400 + r0 + s] = acc[s];
    }
  } else {
    __shared__ float abs_[200];
    __shared__ float us[200];
    if (t < 200) abs_[t] = ab[t];
    __syncthreads();
    if (t < 200) {
      float u = b6[t];
      const float4* w = (const float4*)(W6 + (size_t)t * 400);
      for (int k = 0; k < 50; ++k) u += dot4(w[k], ((const float4*)abs_)[k]);
      us[t] = u;
    }
    __syncthreads();
    if (t < 200) {
      float v = batt[t];
      const float4* w = (const float4*)(Watt + (size_t)t * 600 + 400);
      for (int k = 0; k < 50; ++k) v += dot4(w[k], ((const float4*)us)[k]);
      v1[t] = v;
    }
  }
}

// ---------------------------------------------------------------------------
// x1: X = relu(W1 . cat(E,H,Q) + b1)
// grid (64, 8): 8 batch rows x 50-output tile; 4-way k-split, acc[8]
// ---------------------------------------------------------------------------
__global__ __launch_bounds__(256) void x1_kernel(
    const float* __restrict__ ent_emb, const float* __restrict__ rel_emb,
    const float* __restrict__ H, const int* __restrict__ e_idx,
    const int* __restrict__ q_idx, const float* __restrict__ W1,
    const float* __restrict__ b1, float* __restrict__ X) {
  int b0 = blockIdx.x * 8;
  int j0 = blockIdx.y * 50;
  int t = threadIdx.x;
  __shared__ float cv[8][800];      // 25.6 KB
  __shared__ float part[4][50][9];  // padded stride 9 vs bank conflicts
  for (int i = t; i < 8 * 800; i += 256) {
    int s = i / 800, k = i % 800;
    float v;
    if (k < ENTd)
      v = ent_emb[(size_t)e_idx[b0 + s] * ENTd + k];
    else if (k < ENTd + HISTd)
      v = H[(size_t)(b0 + s) * HISTd + (k - ENTd)];
    else
      v = rel_emb[(size_t)q_idx[b0 + s] * RELd + (k - ENTd - HISTd)];
    cv[s][k] = v;
  }
  __syncthreads();
  if (t < 200) {
    int j = t % 50, kq = t / 50;
    const float4* w = (const float4*)(W1 + (size_t)(j0 + j) * 800 + kq * 200);
    float acc[8] = {0, 0, 0, 0, 0, 0, 0, 0};
    for (int k = 0; k < 50; ++k) {
      float4 wv = w[k];
#pragma unroll
      for (int s = 0; s < 8; ++s)
        acc[s] += dot4(wv, ((const float4*)cv[s])[kq * 50 + k]);
    }
#pragma unroll
    for (int s = 0; s < 8; ++s) part[kq][j][s] = acc[s];
  }
  __syncthreads();
  if (t < 400) {
    int j = t % 50, s = t / 50;
    float v = b1[j0 + j] + part[0][j][s] + part[1][j][s] + part[2][j][s] +
              part[3][j][s];
    X[(size_t)(b0 + s) * ADIMd + j0 + j] = fmaxf(v, 0.f);
  }
}

// ---------------------------------------------------------------------------
// x2: X2 = W2 . X + b2   grid (64, 8): 8 rows x 50-out tile, 4-way k-split
// ---------------------------------------------------------------------------
__global__ __launch_bounds__(256) void x2_kernel(
    const float* __restrict__ X, const float* __restrict__ W2,
    const float* __restrict__ b2, float* __restrict__ X2) {
  int b0 = blockIdx.x * 8;
  int j0 = blockIdx.y * 50;
  int t = threadIdx.x;
  __shared__ float cv[8][400];
  __shared__ float part[4][50][9];
  for (int i = t; i < 8 * 400; i += 256)
    cv[i / 400][i % 400] = X[(size_t)b0 * 400 + i];
  __syncthreads();
  if (t < 200) {
    int j = t % 50, kq = t / 50;
    const float4* w = (const float4*)(W2 + (size_t)(j0 + j) * 400 + kq * 100);
    float acc[8] = {0, 0, 0, 0, 0, 0, 0, 0};
    for (int k = 0; k < 25; ++k) {
      float4 wv = w[k];
#pragma unroll
      for (int s = 0; s < 8; ++s)
        acc[s] += dot4(wv, ((const float4*)cv[s])[kq * 25 + k]);
    }
#pragma unroll
    for (int s = 0; s < 8; ++s) part[kq][j][s] = acc[s];
  }
  __syncthreads();
  if (t < 400) {
    int j = t % 50, s = t / 50;
    X2[(size_t)(b0 + s) * ADIMd + j0 + j] =
        b2[j0 + j] + part[0][j][s] + part[1][j][s] + part[2][j][s] +
        part[3][j][s];
  }
}

// ---------------------------------------------------------------------------
// fused_mid: FOUR batch rows per block (128 blocks x 512 threads):
//   la = S.pe + c ; p = softmax(la) ;
//   attv = Watt_a.X2 + Q.pe + REatt_T.p + v1  (2-thread k-split) ;
//   ratt = softmax(rel . attv) -> out
// ---------------------------------------------------------------------------
__global__ __launch_bounds__(512) void fused_mid_kernel(
    const float* __restrict__ ent_emb, const float* __restrict__ rel_emb,
    const int* __restrict__ pred_id, const float* __restrict__ X2,
    const float* __restrict__ S, const float* __restrict__ cvec,
    const float* __restrict__ Q, const float* __restrict__ REatt_T,
    const float* __restrict__ v1, const float* __restrict__ Watt,
    float* __restrict__ out_ratt) {
  int b0 = blockIdx.x * 4;
  int t = threadIdx.x;
  __shared__ float pe[4][200];
  __shared__ float x2s[4][400];
  __shared__ float pp[4][400];
  __shared__ float av[4][200];
  __shared__ float wred[4][2];
  for (int i = t; i < 800; i += 512)
    pe[i / 200][i % 200] = ent_emb[(size_t)pred_id[b0 + i / 200] * ENTd + i % 200];
  for (int i = t; i < 1600; i += 512)
    x2s[i / 400][i % 400] = X2[(size_t)b0 * 400 + i];
  __syncthreads();
  // la: thread t<400 -> relation r=t, acc over 4 rows
  if (t < 400) {
    float c = cvec[t];
    float acc[4] = {c, c, c, c};
    const float4* sp = (const float4*)(S + (size_t)t * 200);
    for (int k = 0; k < 50; ++k) {
      float4 sv = sp[k];
#pragma unroll
      for (int s = 0; s < 4; ++s) acc[s] += dot4(sv, ((const float4*)pe[s])[k]);
    }
#pragma unroll
    for (int s = 0; s < 4; ++s) pp[s][t] = acc[s];
  }
  __syncthreads();
  int w = t >> 6, lane = t & 63;
  int row = w >> 1, half = w & 1;  // 2 waves per row
  // softmax(pp rows)
  {
    float m = -INFINITY;
    for (int r = half * 64 + lane; r < 400; r += 128) m = fmaxf(m, pp[row][r]);
    m = wave_rmax(m);
    if (lane == 0) wred[row][half] = m;
    __syncthreads();
    float gm = fmaxf(wred[row][0], wred[row][1]);
    __syncthreads();
    float sum = 0.f;
    for (int r = half * 64 + lane; r < 400; r += 128) {
      float e = expf(pp[row][r] - gm);
      pp[row][r] = e;
      sum += e;
    }
    sum = wave_rsum(sum);
    if (lane == 0) wred[row][half] = sum;
    __syncthreads();
    float inv = 1.f / (wred[row][0] + wred[row][1]);
    for (int r = half * 64 + lane; r < 400; r += 128) pp[row][r] *= inv;
  }
  __syncthreads();
  // attv: 2 threads per output j (h=0: v1 + Watt_a.x2 ; h=1: Q.pe + REatt_T.p)
  if (t < 400) {
    int j = t >> 1, h = t & 1;
    float acc[4];
    if (h == 0) {
      float c = v1[j];
      acc[0] = c; acc[1] = c; acc[2] = c; acc[3] = c;
      const float4* wp = (const float4*)(Watt + (size_t)j * 600);
      for (int k = 0; k < 100; ++k) {
        float4 wv = wp[k];
#pragma unroll
        for (int s = 0; s < 4; ++s) acc[s] += dot4(wv, ((const float4*)x2s[s])[k]);
      }
    } else {
      acc[0] = 0.f; acc[1] = 0.f; acc[2] = 0.f; acc[3] = 0.f;
      const float4* qp = (const float4*)(Q + (size_t)j * 200);
      for (int k = 0; k < 50; ++k) {
        float4 wv = qp[k];
#pragma unroll
        for (int s = 0; s < 4; ++s) acc[s] += dot4(wv, ((const float4*)pe[s])[k]);
      }
      const float4* rp = (const float4*)(REatt_T + (size_t)j * 400);
      for (int k = 0; k < 100; ++k) {
        float4 wv = rp[k];
#pragma unroll
        for (int s = 0; s < 4; ++s) acc[s] += dot4(wv, ((const float4*)pp[s])[k]);
      }
    }
#pragma unroll
    for (int s = 0; s < 4; ++s) acc[s] += __shfl_xor(acc[s], 1);
    if (h == 0) {
#pragma unroll
      for (int s = 0; s < 4; ++s) av[s][j] = acc[s];
    }
  }
  __syncthreads();
  // logits -> pp (reuse)
  if (t < 400) {
    float acc[4] = {0, 0, 0, 0};
    const float4* rp = (const float4*)(rel_emb + (size_t)t * 200);
    for (int k = 0; k < 50; ++k) {
      float4 rv = rp[k];
#pragma unroll
      for (int s = 0; s < 4; ++s) acc[s] += dot4(rv, ((const float4*)av[s])[k]);
    }
#pragma unroll
    for (int s = 0; s < 4; ++s) pp[s][t] = acc[s];
  }
  __syncthreads();
  // softmax + write
  {
    float m = -INFINITY;
    for (int r = half * 64 + lane; r < 400; r += 128) m = fmaxf(m, pp[row][r]);
    m = wave_rmax(m);
    if (lane == 0) wred[row][half] = m;
    __syncthreads();
    float gm = fmaxf(wred[row][0], wred[row][1]);
    __syncthreads();
    float sum = 0.f;
    for (int r = half * 64 + lane; r < 400; r += 128) {
      float e = expf(pp[row][r] - gm);
      pp[row][r] = e;
      sum += e;
    }
    sum = wave_rsum(sum);
    if (lane == 0) wred[row][half] = sum;
    __syncthreads();
    float inv = 1.f / (wred[row][0] + wred[row][1]);
    for (int r = half * 64 + lane; r < 400; r += 128)
      out_ratt[(size_t)(b0 + row) * 400 + r] = pp[row][r] * inv;
  }
}

// ---------------------------------------------------------------------------
// scores: one row per block, 512 threads, 2 threads per action (rel/ent halves)
// ---------------------------------------------------------------------------
__global__ __launch_bounds__(512) void scores_kernel(
    const float* __restrict__ X2, const float* __restrict__ rel_emb,
    const float* __restrict__ ent_emb, const int* __restrict__ r_space,
    const int* __restrict__ e_space, const float* __restrict__ mask,
    float* __restrict__ out_dist, float* __restrict__ out_ent) {
  int b = blockIdx.x;
  int t = threadIdx.x;
  __shared__ float x2s[400];
  __shared__ float wred[8];
  if (t < 400) x2s[t] = X2[(size_t)b * ADIMd + t];
  __syncthreads();
  int a = t >> 1, h = t & 1;
  float acc = 0.f;
  if (h == 0) {
    int r = r_space[(size_t)b * AA + a];
    const float4* rp = (const float4*)(rel_emb + (size_t)r * RELd);
    for (int k = 0; k < 50; ++k) acc += dot4(rp[k], ((const float4*)x2s)[k]);
  } else {
    int ei = e_space[(size_t)b * AA + a];
    const float4* ep = (const float4*)(ent_emb + (size_t)ei * ENTd);
    for (int k = 0; k < 50; ++k) acc += dot4(ep[k], ((const float4*)x2s)[50 + k]);
  }
  acc += __shfl_xor(acc, 1);
  float score = acc - (1.f - mask[(size_t)b * AA + a]) * 1e31f;
  int w = t >> 6, lane = t & 63;
  float m = wave_rmax(score);
  if (lane == 0) wred[w] = m;
  __syncthreads();
  float gm = wred[0];
#pragma unroll
  for (int i = 1; i < 8; ++i) gm = fmaxf(gm, wred[i]);
  __syncthreads();
  float e = expf(score - gm);
  float sw = wave_rsum(e);
  if (lane == 0) wred[w] = sw;
  __syncthreads();
  float gs = 0.f;
#pragma unroll
  for (int i = 0; i < 8; ++i) gs += wred[i];
  gs *= 0.5f;
  float p = e / gs;
  if (h == 0) out_dist[(size_t)b * AA + a] = p;
  float entv = -p * logf(p + 1e-20f);
  float ew = wave_rsum(entv);
  __syncthreads();
  if (lane == 0) wred[w] = ew;
  __syncthreads();
  if (t == 0) {
    float s = 0.f;
#pragma unroll
    for (int i = 0; i < 8; ++i) s += wred[i];
    out_ent[b] = s * 0.5f;
  }
}

// ---------------------------------------------------------------------------
extern "C" void kernel_launch(void* const* d_in, const int* in_sizes, int n_in,
                              void* d_out, int out_size, void* d_ws,
                              size_t ws_size, hipStream_t stream) {
  const float* H = (const float*)d_in[0];
  const float* mask = (const float*)d_in[1];
  const float* ent_emb = (const float*)d_in[2];
  const float* rel_emb = (const float*)d_in[3];
  const float* W1 = (const float*)d_in[4];
  const float* b1 = (const float*)d_in[5];
  const float* W2 = (const float*)d_in[6];
  const float* b2 = (const float*)d_in[7];
  const float* W3 = (const float*)d_in[8];
  const float* b3 = (const float*)d_in[9];
  const float* W4 = (const float*)d_in[10];
  const float* b4 = (const float*)d_in[11];
  const float* W5 = (const float*)d_in[12];
  const float* b5 = (const float*)d_in[13];
  const float* W6 = (const float*)d_in[14];
  const float* b6 = (const float*)d_in[15];
  const float* Watt = (const float*)d_in[16];
  const float* batt = (const float*)d_in[17];
  const int* e_idx = (const int*)d_in[18];
  const int* q_idx = (const int*)d_in[19];
  const int* pred_id = (const int*)d_in[20];
  const int* r_space = (const int*)d_in[21];
  const int* e_space = (const int*)d_in[22];

  float* ws = (float*)d_ws;
  float* RK = ws;                  // 80000
  float* S = ws + 80000;           // 80000
  float* cvec = ws + 160000;       // 512
  float* P = ws + 160512;          // 40000
  float* Q = ws + 200512;          // 40000
  float* W6bb = ws + 240512;       // 40000
  float* REatt_T = ws + 280512;    // 80000 (transposed [200][400])
  float* ab = ws + 360512;         // 256
  float* v1 = ws + 360768;         // 256
  float* X = ws + 361024;          // 204800
  float* X2 = ws + 565824;         // 204800

  float* out = (float*)d_out;
  float* out_dist = out;                 // [512,256]
  float* out_ent = out + BB * AA;        // [512]
  float* out_ratt = out + BB * AA + BB;  // [512,400]

  hipLaunchKernelGGL(prep1_kernel, dim3(101), dim3(256), 0, stream, rel_emb,
                     W4, b4, W5, b5, W6, Watt, RK, P, W6bb, ab);
  hipLaunchKernelGGL(prep2_kernel, dim3(126), dim3(256), 0, stream, rel_emb,
                     W3, b3, W6, Watt, batt, b6, RK, P, W6bb, ab, S, cvec, Q,
                     REatt_T, v1);
  hipLaunchKernelGGL(x1_kernel, dim3(64, 8), dim3(256), 0, stream, ent_emb,
                     rel_emb, H, e_idx, q_idx, W1, b1, X);
  hipLaunchKernelGGL(x2_kernel, dim3(64, 8), dim3(256), 0, stream, X, W2, b2,
                     X2);
  hipLaunchKernelGGL(fused_mid_kernel, dim3(128), dim3(512), 0, stream,
                     ent_emb, rel_emb, pred_id, X2, S, cvec, Q, REatt_T, v1,
                     Watt, out_ratt);
  hipLaunchKernelGGL(scores_kernel, dim3(512), dim3(512), 0, stream, X2,
                     rel_emb, ent_emb, r_space, e_space, mask, out_dist,
                     out_ent);
}

// Round 5
// 159.311 us; speedup vs baseline: 1.1288x; 1.0430x over previous
//
#include <hip/hip_runtime.h>
#include <cstdint>
#include <cstddef>

#define BB 512
#define NEn 100000
#define NRr 400
#define AA 256
#define ENTd 200
#define RELd 200
#define HISTd 400
#define ADIMd 400

__device__ __forceinline__ float dot4(const float4 a, const float4 b) {
  return a.x * b.x + a.y * b.y + a.z * b.z + a.w * b.w;
}
__device__ __forceinline__ float wave_rmax(float v) {
#pragma unroll
  for (int off = 32; off > 0; off >>= 1) v = fmaxf(v, __shfl_xor(v, off));
  return v;
}
__device__ __forceinline__ float wave_rsum(float v) {
#pragma unroll
  for (int off = 32; off > 0; off >>= 1) v += __shfl_xor(v, off);
  return v;
}

// ---------------------------------------------------------------------------
// prep1: batch-invariant stage 1. (grouped loads for ILP)
// ---------------------------------------------------------------------------
__global__ __launch_bounds__(256) void prep1_kernel(
    const float* __restrict__ rel_emb, const float* __restrict__ W4,
    const float* __restrict__ b4, const float* __restrict__ W5,
    const float* __restrict__ b5, const float* __restrict__ W6,
    const float* __restrict__ Watt, float* __restrict__ RK,
    float* __restrict__ P, float* __restrict__ W6bb, float* __restrict__ ab) {
  int t = threadIdx.x;
  int blk = blockIdx.x;
  if (blk == 0) {
    __shared__ float rs[RELd];
    if (t < RELd) {
      float s = 0.f;
      for (int r = 0; r < NRr; r += 4) {
        float a = rel_emb[(size_t)r * RELd + t];
        float b = rel_emb[(size_t)(r + 1) * RELd + t];
        float c = rel_emb[(size_t)(r + 2) * RELd + t];
        float d = rel_emb[(size_t)(r + 3) * RELd + t];
        s += a + b + c + d;
      }
      rs[t] = s;
    }
    __syncthreads();
    if (t < RELd) {
      float acc = b5[t];
      const float4* w = (const float4*)(W5 + (size_t)t * 400);
      const float4* rv = (const float4*)rs;
      for (int k = 0; k < 50; k += 5) {
        float4 g0 = w[k], g1 = w[k + 1], g2 = w[k + 2], g3 = w[k + 3],
               g4 = w[k + 4];
        acc += dot4(g0, rv[k]) + dot4(g1, rv[k + 1]) + dot4(g2, rv[k + 2]) +
               dot4(g3, rv[k + 3]) + dot4(g4, rv[k + 4]);
      }
      ab[t] = acc;
    }
  } else if (blk <= 50) {
    int r0 = (blk - 1) * 8;
    __shared__ float re[8][RELd];
    for (int i = t; i < 8 * RELd; i += 256)
      re[i / RELd][i % RELd] = rel_emb[(size_t)(r0 + i / RELd) * RELd + i % RELd];
    __syncthreads();
    if (t < RELd) {
      float bv = b4[t];
      float acc[8];
#pragma unroll
      for (int s = 0; s < 8; ++s) acc[s] = bv;
      const float4* w = (const float4*)(W4 + (size_t)t * RELd);
      for (int k = 0; k < 50; k += 5) {
        float4 g0 = w[k], g1 = w[k + 1], g2 = w[k + 2], g3 = w[k + 3],
               g4 = w[k + 4];
#pragma unroll
        for (int s = 0; s < 8; ++s) {
          const float4* rv = (const float4*)re[s];
          acc[s] += dot4(g0, rv[k]) + dot4(g1, rv[k + 1]) +
                    dot4(g2, rv[k + 2]) + dot4(g3, rv[k + 3]) +
                    dot4(g4, rv[k + 4]);
        }
      }
#pragma unroll
      for (int s = 0; s < 8; ++s) RK[(size_t)(r0 + s) * RELd + t] = acc[s];
    }
  } else if (blk <= 75) {
    int i0 = (blk - 51) * 8;
    __shared__ float w6s[8][200];
    for (int i = t; i < 8 * 200; i += 256)
      w6s[i / 200][i % 200] = W6[(size_t)(i0 + i / 200) * 400 + i % 200];
    __syncthreads();
    if (t < 200) {
      int k = t;
      float acc[8] = {0, 0, 0, 0, 0, 0, 0, 0};
      for (int j = 0; j < 200; j += 4) {
        float r0v = W5[(size_t)j * 400 + 200 + k];
        float r1v = W5[(size_t)(j + 1) * 400 + 200 + k];
        float r2v = W5[(size_t)(j + 2) * 400 + 200 + k];
        float r3v = W5[(size_t)(j + 3) * 400 + 200 + k];
#pragma unroll
        for (int s = 0; s < 8; ++s)
          acc[s] += w6s[s][j] * r0v + w6s[s][j + 1] * r1v +
                    w6s[s][j + 2] * r2v + w6s[s][j + 3] * r3v;
      }
#pragma unroll
      for (int s = 0; s < 8; ++s) P[(size_t)(i0 + s) * 200 + k] = 400.f * acc[s];
    }
  } else {
    int u0 = (blk - 76) * 8;
    __shared__ float wbs[8][200];
    for (int i = t; i < 8 * 200; i += 256)
      wbs[i / 200][i % 200] = Watt[(size_t)(u0 + i / 200) * 600 + 400 + i % 200];
    __syncthreads();
    if (t < 200) {
      int j = t;
      float acc[8] = {0, 0, 0, 0, 0, 0, 0, 0};
      for (int i = 0; i < 200; i += 4) {
        float r0v = W6[(size_t)i * 400 + 200 + j];
        float r1v = W6[(size_t)(i + 1) * 400 + 200 + j];
        float r2v = W6[(size_t)(i + 2) * 400 + 200 + j];
        float r3v = W6[(size_t)(i + 3) * 400 + 200 + j];
#pragma unroll
        for (int s = 0; s < 8; ++s)
          acc[s] += wbs[s][i] * r0v + wbs[s][i + 1] * r1v +
                    wbs[s][i + 2] * r2v + wbs[s][i + 3] * r3v;
      }
#pragma unroll
      for (int s = 0; s < 8; ++s) W6bb[(size_t)(u0 + s) * 200 + j] = acc[s];
    }
  }
}

// ---------------------------------------------------------------------------
// prep2: batch-invariant stage 2. (grouped loads)
// ---------------------------------------------------------------------------
__global__ __launch_bounds__(256) void prep2_kernel(
    const float* __restrict__ rel_emb, const float* __restrict__ W3,
    const float* __restrict__ b3, const float* __restrict__ W6,
    const float* __restrict__ Watt, const float* __restrict__ batt,
    const float* __restrict__ b6, const float* __restrict__ RK,
    const float* __restrict__ P, const float* __restrict__ W6bb,
    const float* __restrict__ ab, float* __restrict__ S,
    float* __restrict__ cvec, float* __restrict__ Q,
    float* __restrict__ REatt_T, float* __restrict__ v1) {
  int t = threadIdx.x;
  int blk = blockIdx.x;
  if (blk < 50) {
    int r0 = blk * 8;
    __shared__ float rks[8][200];
    __shared__ float b3s[200];
    for (int i = t; i < 8 * 200; i += 256)
      rks[i / 200][i % 200] = RK[(size_t)(r0 + i / 200) * 200 + i % 200];
    if (t < 200) b3s[t] = b3[t];
    __syncthreads();
    if (t < 200) {
      int i = t;
      float acc[8] = {0, 0, 0, 0, 0, 0, 0, 0};
      for (int j = 0; j < 200; j += 4) {
        float w0 = W3[(size_t)j * 200 + i];
        float w1 = W3[(size_t)(j + 1) * 200 + i];
        float w2 = W3[(size_t)(j + 2) * 200 + i];
        float w3v = W3[(size_t)(j + 3) * 200 + i];
#pragma unroll
        for (int s = 0; s < 8; ++s)
          acc[s] += w0 * rks[s][j] + w1 * rks[s][j + 1] + w2 * rks[s][j + 2] +
                    w3v * rks[s][j + 3];
      }
#pragma unroll
      for (int s = 0; s < 8; ++s) S[(size_t)(r0 + s) * 200 + i] = acc[s];
    }
    {
      int w = t >> 6, lane = t & 63;
      float p0 = 0.f, p1 = 0.f;
      for (int j = lane; j < 200; j += 64) {
        p0 += b3s[j] * rks[w][j];
        p1 += b3s[j] * rks[w + 4][j];
      }
      p0 = wave_rsum(p0);
      p1 = wave_rsum(p1);
      if (lane == 0) {
        cvec[r0 + w] = p0;
        cvec[r0 + w + 4] = p1;
      }
    }
  } else if (blk < 75) {
    int u0 = (blk - 50) * 8;
    __shared__ float wbs[8][200];
    for (int i = t; i < 8 * 200; i += 256)
      wbs[i / 200][i % 200] = Watt[(size_t)(u0 + i / 200) * 600 + 400 + i % 200];
    __syncthreads();
    if (t < 200) {
      int k = t;
      float acc[8] = {0, 0, 0, 0, 0, 0, 0, 0};
      for (int i = 0; i < 200; i += 4) {
        float r0v = P[(size_t)i * 200 + k];
        float r1v = P[(size_t)(i + 1) * 200 + k];
        float r2v = P[(size_t)(i + 2) * 200 + k];
        float r3v = P[(size_t)(i + 3) * 200 + k];
#pragma unroll
        for (int s = 0; s < 8; ++s)
          acc[s] += wbs[s][i] * r0v + wbs[s][i + 1] * r1v +
                    wbs[s][i + 2] * r2v + wbs[s][i + 3] * r3v;
      }
#pragma unroll
      for (int s = 0; s < 8; ++s) Q[(size_t)(u0 + s) * 200 + k] = acc[s];
    }
  } else if (blk < 125) {
    int r0 = (blk - 75) * 8;
    __shared__ float rels[8][200];
    for (int i = t; i < 8 * 200; i += 256)
      rels[i / 200][i % 200] = rel_emb[(size_t)(r0 + i / 200) * 200 + i % 200];
    __syncthreads();
    if (t < 200) {
      float acc[8] = {0, 0, 0, 0, 0, 0, 0, 0};
      const float4* w = (const float4*)(W6bb + (size_t)t * 200);
      for (int k = 0; k < 50; k += 5) {
        float4 g0 = w[k], g1 = w[k + 1], g2 = w[k + 2], g3 = w[k + 3],
               g4 = w[k + 4];
#pragma unroll
        for (int s = 0; s < 8; ++s) {
          const float4* rv = (const float4*)rels[s];
          acc[s] += dot4(g0, rv[k]) + dot4(g1, rv[k + 1]) +
                    dot4(g2, rv[k + 2]) + dot4(g3, rv[k + 3]) +
                    dot4(g4, rv[k + 4]);
        }
      }
#pragma unroll
      for (int s = 0; s < 8; ++s) REatt_T[(size_t)t * 400 + r0 + s] = acc[s];
    }
  } else {
    __shared__ float abs_[200];
    __shared__ float us[200];
    if (t < 200) abs_[t] = ab[t];
    __syncthreads();
    if (t < 200) {
      float u = b6[t];
      const float4* w = (const float4*)(W6 + (size_t)t * 400);
      const float4* rv = (const float4*)abs_;
      for (int k = 0; k < 50; k += 5) {
        float4 g0 = w[k], g1 = w[k + 1], g2 = w[k + 2], g3 = w[k + 3],
               g4 = w[k + 4];
        u += dot4(g0, rv[k]) + dot4(g1, rv[k + 1]) + dot4(g2, rv[k + 2]) +
             dot4(g3, rv[k + 3]) + dot4(g4, rv[k + 4]);
      }
      us[t] = u;
    }
    __syncthreads();
    if (t < 200) {
      float v = batt[t];
      const float4* w = (const float4*)(Watt + (size_t)t * 600 + 400);
      const float4* rv = (const float4*)us;
      for (int k = 0; k < 50; k += 5) {
        float4 g0 = w[k], g1 = w[k + 1], g2 = w[k + 2], g3 = w[k + 3],
               g4 = w[k + 4];
        v += dot4(g0, rv[k]) + dot4(g1, rv[k + 1]) + dot4(g2, rv[k + 2]) +
             dot4(g3, rv[k + 3]) + dot4(g4, rv[k + 4]);
      }
      v1[t] = v;
    }
  }
}

// ---------------------------------------------------------------------------
// x1: X = relu(W1 . cat(E,H,Q) + b1)
// grid (64, 8): 8 batch rows x 50-output tile; 4-way k-split, acc[8], 5-group
// ---------------------------------------------------------------------------
__global__ __launch_bounds__(256) void x1_kernel(
    const float* __restrict__ ent_emb, const float* __restrict__ rel_emb,
    const float* __restrict__ H, const int* __restrict__ e_idx,
    const int* __restrict__ q_idx, const float* __restrict__ W1,
    const float* __restrict__ b1, float* __restrict__ X) {
  int b0 = blockIdx.x * 8;
  int j0 = blockIdx.y * 50;
  int t = threadIdx.x;
  __shared__ float cv[8][800];
  __shared__ float part[4][50][9];
  for (int i = t; i < 8 * 800; i += 256) {
    int s = i / 800, k = i % 800;
    float v;
    if (k < ENTd)
      v = ent_emb[(size_t)e_idx[b0 + s] * ENTd + k];
    else if (k < ENTd + HISTd)
      v = H[(size_t)(b0 + s) * HISTd + (k - ENTd)];
    else
      v = rel_emb[(size_t)q_idx[b0 + s] * RELd + (k - ENTd - HISTd)];
    cv[s][k] = v;
  }
  __syncthreads();
  if (t < 200) {
    int j = t % 50, kq = t / 50;
    const float4* w = (const float4*)(W1 + (size_t)(j0 + j) * 800 + kq * 200);
    float acc[8] = {0, 0, 0, 0, 0, 0, 0, 0};
    for (int k = 0; k < 50; k += 5) {
      float4 g0 = w[k], g1 = w[k + 1], g2 = w[k + 2], g3 = w[k + 3],
             g4 = w[k + 4];
#pragma unroll
      for (int s = 0; s < 8; ++s) {
        const float4* rv = ((const float4*)cv[s]) + kq * 50;
        acc[s] += dot4(g0, rv[k]) + dot4(g1, rv[k + 1]) + dot4(g2, rv[k + 2]) +
                  dot4(g3, rv[k + 3]) + dot4(g4, rv[k + 4]);
      }
    }
#pragma unroll
    for (int s = 0; s < 8; ++s) part[kq][j][s] = acc[s];
  }
  __syncthreads();
  if (t < 400) {
    int j = t % 50, s = t / 50;
    float v = b1[j0 + j] + part[0][j][s] + part[1][j][s] + part[2][j][s] +
              part[3][j][s];
    X[(size_t)(b0 + s) * ADIMd + j0 + j] = fmaxf(v, 0.f);
  }
}

// ---------------------------------------------------------------------------
// x2: X2 = W2 . X + b2   grid (64, 8), 4-way k-split, 5-group
// ---------------------------------------------------------------------------
__global__ __launch_bounds__(256) void x2_kernel(
    const float* __restrict__ X, const float* __restrict__ W2,
    const float* __restrict__ b2, float* __restrict__ X2) {
  int b0 = blockIdx.x * 8;
  int j0 = blockIdx.y * 50;
  int t = threadIdx.x;
  __shared__ float cv[8][400];
  __shared__ float part[4][50][9];
  for (int i = t; i < 8 * 400; i += 256)
    cv[i / 400][i % 400] = X[(size_t)b0 * 400 + i];
  __syncthreads();
  if (t < 200) {
    int j = t % 50, kq = t / 50;
    const float4* w = (const float4*)(W2 + (size_t)(j0 + j) * 400 + kq * 100);
    float acc[8] = {0, 0, 0, 0, 0, 0, 0, 0};
    for (int k = 0; k < 25; k += 5) {
      float4 g0 = w[k], g1 = w[k + 1], g2 = w[k + 2], g3 = w[k + 3],
             g4 = w[k + 4];
#pragma unroll
      for (int s = 0; s < 8; ++s) {
        const float4* rv = ((const float4*)cv[s]) + kq * 25;
        acc[s] += dot4(g0, rv[k]) + dot4(g1, rv[k + 1]) + dot4(g2, rv[k + 2]) +
                  dot4(g3, rv[k + 3]) + dot4(g4, rv[k + 4]);
      }
    }
#pragma unroll
    for (int s = 0; s < 8; ++s) part[kq][j][s] = acc[s];
  }
  __syncthreads();
  if (t < 400) {
    int j = t % 50, s = t / 50;
    X2[(size_t)(b0 + s) * ADIMd + j0 + j] =
        b2[j0 + j] + part[0][j][s] + part[1][j][s] + part[2][j][s] +
        part[3][j][s];
  }
}

// ---------------------------------------------------------------------------
// fused_mid: TWO batch rows per block (256 blocks x 512 threads), 5-grouped:
//   la = S.pe + c ; p = softmax(la) ;
//   attv = Watt_a.X2 + Q.pe + REatt_T.p + v1  (2-thread k-split) ;
//   ratt = softmax(rel . attv) -> out
// ---------------------------------------------------------------------------
__global__ __launch_bounds__(512) void fused_mid_kernel(
    const float* __restrict__ ent_emb, const float* __restrict__ rel_emb,
    const int* __restrict__ pred_id, const float* __restrict__ X2,
    const float* __restrict__ S, const float* __restrict__ cvec,
    const float* __restrict__ Q, const float* __restrict__ REatt_T,
    const float* __restrict__ v1, const float* __restrict__ Watt,
    float* __restrict__ out_ratt) {
  int b0 = blockIdx.x * 2;
  int t = threadIdx.x;
  __shared__ float pe[2][200];
  __shared__ float x2s[2][400];
  __shared__ float pp[2][400];
  __shared__ float av[2][200];
  __shared__ float wred[2][4];
  if (t < 400)
    pe[t / 200][t % 200] = ent_emb[(size_t)pred_id[b0 + t / 200] * ENTd + t % 200];
  else {
    int i = t - 400;  // 112 threads idle for this; x2s loaded below by all
  }
  for (int i = t; i < 800; i += 512) x2s[i / 400][i % 400] = X2[(size_t)b0 * 400 + i];
  __syncthreads();
  // la: thread t<400 -> relation r=t
  if (t < 400) {
    float c = cvec[t];
    float a0 = c, a1 = c;
    const float4* sp = (const float4*)(S + (size_t)t * 200);
    const float4* p0 = (const float4*)pe[0];
    const float4* p1 = (const float4*)pe[1];
    for (int k = 0; k < 50; k += 5) {
      float4 g0 = sp[k], g1 = sp[k + 1], g2 = sp[k + 2], g3 = sp[k + 3],
             g4 = sp[k + 4];
      a0 += dot4(g0, p0[k]) + dot4(g1, p0[k + 1]) + dot4(g2, p0[k + 2]) +
            dot4(g3, p0[k + 3]) + dot4(g4, p0[k + 4]);
      a1 += dot4(g0, p1[k]) + dot4(g1, p1[k + 1]) + dot4(g2, p1[k + 2]) +
            dot4(g3, p1[k + 3]) + dot4(g4, p1[k + 4]);
    }
    pp[0][t] = a0;
    pp[1][t] = a1;
  }
  __syncthreads();
  int w = t >> 6, lane = t & 63;
  int row = w >> 2, q = w & 3;  // 4 waves per row
  // softmax(pp rows)
  {
    float m = -INFINITY;
    for (int r = q * 64 + lane; r < 400; r += 256) m = fmaxf(m, pp[row][r]);
    m = wave_rmax(m);
    if (lane == 0) wred[row][q] = m;
    __syncthreads();
    float gm = fmaxf(fmaxf(wred[row][0], wred[row][1]),
                     fmaxf(wred[row][2], wred[row][3]));
    __syncthreads();
    float sum = 0.f;
    for (int r = q * 64 + lane; r < 400; r += 256) {
      float e = expf(pp[row][r] - gm);
      pp[row][r] = e;
      sum += e;
    }
    sum = wave_rsum(sum);
    if (lane == 0) wred[row][q] = sum;
    __syncthreads();
    float inv = 1.f / (wred[row][0] + wred[row][1] + wred[row][2] + wred[row][3]);
    for (int r = q * 64 + lane; r < 400; r += 256) pp[row][r] *= inv;
  }
  __syncthreads();
  // attv: 2 threads per output j
  if (t < 400) {
    int j = t >> 1, h = t & 1;
    float a0, a1;
    if (h == 0) {
      a0 = v1[j];
      a1 = a0;
      const float4* wp = (const float4*)(Watt + (size_t)j * 600);
      const float4* x0 = (const float4*)x2s[0];
      const float4* x1v = (const float4*)x2s[1];
      for (int k = 0; k < 100; k += 5) {
        float4 g0 = wp[k], g1 = wp[k + 1], g2 = wp[k + 2], g3 = wp[k + 3],
               g4 = wp[k + 4];
        a0 += dot4(g0, x0[k]) + dot4(g1, x0[k + 1]) + dot4(g2, x0[k + 2]) +
              dot4(g3, x0[k + 3]) + dot4(g4, x0[k + 4]);
        a1 += dot4(g0, x1v[k]) + dot4(g1, x1v[k + 1]) + dot4(g2, x1v[k + 2]) +
              dot4(g3, x1v[k + 3]) + dot4(g4, x1v[k + 4]);
      }
    } else {
      a0 = 0.f;
      a1 = 0.f;
      const float4* qp = (const float4*)(Q + (size_t)j * 200);
      const float4* p0 = (const float4*)pe[0];
      const float4* p1 = (const float4*)pe[1];
      for (int k = 0; k < 50; k += 5) {
        float4 g0 = qp[k], g1 = qp[k + 1], g2 = qp[k + 2], g3 = qp[k + 3],
               g4 = qp[k + 4];
        a0 += dot4(g0, p0[k]) + dot4(g1, p0[k + 1]) + dot4(g2, p0[k + 2]) +
              dot4(g3, p0[k + 3]) + dot4(g4, p0[k + 4]);
        a1 += dot4(g0, p1[k]) + dot4(g1, p1[k + 1]) + dot4(g2, p1[k + 2]) +
              dot4(g3, p1[k + 3]) + dot4(g4, p1[k + 4]);
      }
      const float4* rp = (const float4*)(REatt_T + (size_t)j * 400);
      const float4* q0 = (const float4*)pp[0];
      const float4* q1 = (const float4*)pp[1];
      for (int k = 0; k < 100; k += 5) {
        float4 g0 = rp[k], g1 = rp[k + 1], g2 = rp[k + 2], g3 = rp[k + 3],
               g4 = rp[k + 4];
        a0 += dot4(g0, q0[k]) + dot4(g1, q0[k + 1]) + dot4(g2, q0[k + 2]) +
              dot4(g3, q0[k + 3]) + dot4(g4, q0[k + 4]);
        a1 += dot4(g0, q1[k]) + dot4(g1, q1[k + 1]) + dot4(g2, q1[k + 2]) +
              dot4(g3, q1[k + 3]) + dot4(g4, q1[k + 4]);
      }
    }
    a0 += __shfl_xor(a0, 1);
    a1 += __shfl_xor(a1, 1);
    if (h == 0) {
      av[0][j] = a0;
      av[1][j] = a1;
    }
  }
  __syncthreads();
  // logits -> pp (reuse)
  if (t < 400) {
    const float4* rp = (const float4*)(rel_emb + (size_t)t * 200);
    const float4* a0v = (const float4*)av[0];
    const float4* a1v = (const float4*)av[1];
    float l0 = 0.f, l1 = 0.f;
    for (int k = 0; k < 50; k += 5) {
      float4 g0 = rp[k], g1 = rp[k + 1], g2 = rp[k + 2], g3 = rp[k + 3],
             g4 = rp[k + 4];
      l0 += dot4(g0, a0v[k]) + dot4(g1, a0v[k + 1]) + dot4(g2, a0v[k + 2]) +
            dot4(g3, a0v[k + 3]) + dot4(g4, a0v[k + 4]);
      l1 += dot4(g0, a1v[k]) + dot4(g1, a1v[k + 1]) + dot4(g2, a1v[k + 2]) +
            dot4(g3, a1v[k + 3]) + dot4(g4, a1v[k + 4]);
    }
    pp[0][t] = l0;
    pp[1][t] = l1;
  }
  __syncthreads();
  // softmax + write
  {
    float m = -INFINITY;
    for (int r = q * 64 + lane; r < 400; r += 256) m = fmaxf(m, pp[row][r]);
    m = wave_rmax(m);
    if (lane == 0) wred[row][q] = m;
    __syncthreads();
    float gm = fmaxf(fmaxf(wred[row][0], wred[row][1]),
                     fmaxf(wred[row][2], wred[row][3]));
    __syncthreads();
    float sum = 0.f;
    for (int r = q * 64 + lane; r < 400; r += 256) {
      float e = expf(pp[row][r] - gm);
      pp[row][r] = e;
      sum += e;
    }
    sum = wave_rsum(sum);
    if (lane == 0) wred[row][q] = sum;
    __syncthreads();
    float inv = 1.f / (wred[row][0] + wred[row][1] + wred[row][2] + wred[row][3]);
    for (int r = q * 64 + lane; r < 400; r += 256)
      out_ratt[(size_t)(b0 + row) * 400 + r] = pp[row][r] * inv;
  }
}

// ---------------------------------------------------------------------------
// scores: one row per block, 512 threads, 2 threads per action, 5-grouped
// ---------------------------------------------------------------------------
__global__ __launch_bounds__(512) void scores_kernel(
    const float* __restrict__ X2, const float* __restrict__ rel_emb,
    const float* __restrict__ ent_emb, const int* __restrict__ r_space,
    const int* __restrict__ e_space, const float* __restrict__ mask,
    float* __restrict__ out_dist, float* __restrict__ out_ent) {
  int b = blockIdx.x;
  int t = threadIdx.x;
  __shared__ float x2s[400];
  __shared__ float wred[8];
  if (t < 400) x2s[t] = X2[(size_t)b * ADIMd + t];
  __syncthreads();
  int a = t >> 1, h = t & 1;
  float acc = 0.f;
  if (h == 0) {
    int r = r_space[(size_t)b * AA + a];
    const float4* rp = (const float4*)(rel_emb + (size_t)r * RELd);
    const float4* xv = (const float4*)x2s;
    for (int k = 0; k < 50; k += 5) {
      float4 g0 = rp[k], g1 = rp[k + 1], g2 = rp[k + 2], g3 = rp[k + 3],
             g4 = rp[k + 4];
      acc += dot4(g0, xv[k]) + dot4(g1, xv[k + 1]) + dot4(g2, xv[k + 2]) +
             dot4(g3, xv[k + 3]) + dot4(g4, xv[k + 4]);
    }
  } else {
    int ei = e_space[(size_t)b * AA + a];
    const float4* ep = (const float4*)(ent_emb + (size_t)ei * ENTd);
    const float4* xv = ((const float4*)x2s) + 50;
    for (int k = 0; k < 50; k += 5) {
      float4 g0 = ep[k], g1 = ep[k + 1], g2 = ep[k + 2], g3 = ep[k + 3],
             g4 = ep[k + 4];
      acc += dot4(g0, xv[k]) + dot4(g1, xv[k + 1]) + dot4(g2, xv[k + 2]) +
             dot4(g3, xv[k + 3]) + dot4(g4, xv[k + 4]);
    }
  }
  acc += __shfl_xor(acc, 1);
  float score = acc - (1.f - mask[(size_t)b * AA + a]) * 1e31f;
  int w = t >> 6, lane = t & 63;
  float m = wave_rmax(score);
  if (lane == 0) wred[w] = m;
  __syncthreads();
  float gm = wred[0];
#pragma unroll
  for (int i = 1; i < 8; ++i) gm = fmaxf(gm, wred[i]);
  __syncthreads();
  float e = expf(score - gm);
  float sw = wave_rsum(e);
  if (lane == 0) wred[w] = sw;
  __syncthreads();
  float gs = 0.f;
#pragma unroll
  for (int i = 0; i < 8; ++i) gs += wred[i];
  gs *= 0.5f;
  float p = e / gs;
  if (h == 0) out_dist[(size_t)b * AA + a] = p;
  float entv = -p * logf(p + 1e-20f);
  float ew = wave_rsum(entv);
  __syncthreads();
  if (lane == 0) wred[w] = ew;
  __syncthreads();
  if (t == 0) {
    float s = 0.f;
#pragma unroll
    for (int i = 0; i < 8; ++i) s += wred[i];
    out_ent[b] = s * 0.5f;
  }
}

// ---------------------------------------------------------------------------
extern "C" void kernel_launch(void* const* d_in, const int* in_sizes, int n_in,
                              void* d_out, int out_size, void* d_ws,
                              size_t ws_size, hipStream_t stream) {
  const float* H = (const float*)d_in[0];
  const float* mask = (const float*)d_in[1];
  const float* ent_emb = (const float*)d_in[2];
  const float* rel_emb = (const float*)d_in[3];
  const float* W1 = (const float*)d_in[4];
  const float* b1 = (const float*)d_in[5];
  const float* W2 = (const float*)d_in[6];
  const float* b2 = (const float*)d_in[7];
  const float* W3 = (const float*)d_in[8];
  const float* b3 = (const float*)d_in[9];
  const float* W4 = (const float*)d_in[10];
  const float* b4 = (const float*)d_in[11];
  const float* W5 = (const float*)d_in[12];
  const float* b5 = (const float*)d_in[13];
  const float* W6 = (const float*)d_in[14];
  const float* b6 = (const float*)d_in[15];
  const float* Watt = (const float*)d_in[16];
  const float* batt = (const float*)d_in[17];
  const int* e_idx = (const int*)d_in[18];
  const int* q_idx = (const int*)d_in[19];
  const int* pred_id = (const int*)d_in[20];
  const int* r_space = (const int*)d_in[21];
  const int* e_space = (const int*)d_in[22];

  float* ws = (float*)d_ws;
  float* RK = ws;                  // 80000
  float* S = ws + 80000;           // 80000
  float* cvec = ws + 160000;       // 512
  float* P = ws + 160512;          // 40000
  float* Q = ws + 200512;          // 40000
  float* W6bb = ws + 240512;       // 40000
  float* REatt_T = ws + 280512;    // 80000 (transposed [200][400])
  float* ab = ws + 360512;         // 256
  float* v1 = ws + 360768;         // 256
  float* X = ws + 361024;          // 204800
  float* X2 = ws + 565824;         // 204800

  float* out = (float*)d_out;
  float* out_dist = out;                 // [512,256]
  float* out_ent = out + BB * AA;        // [512]
  float* out_ratt = out + BB * AA + BB;  // [512,400]

  hipLaunchKernelGGL(prep1_kernel, dim3(101), dim3(256), 0, stream, rel_emb,
                     W4, b4, W5, b5, W6, Watt, RK, P, W6bb, ab);
  hipLaunchKernelGGL(prep2_kernel, dim3(126), dim3(256), 0, stream, rel_emb,
                     W3, b3, W6, Watt, batt, b6, RK, P, W6bb, ab, S, cvec, Q,
                     REatt_T, v1);
  hipLaunchKernelGGL(x1_kernel, dim3(64, 8), dim3(256), 0, stream, ent_emb,
                     rel_emb, H, e_idx, q_idx, W1, b1, X);
  hipLaunchKernelGGL(x2_kernel, dim3(64, 8), dim3(256), 0, stream, X, W2, b2,
                     X2);
  hipLaunchKernelGGL(fused_mid_kernel, dim3(256), dim3(512), 0, stream,
                     ent_emb, rel_emb, pred_id, X2, S, cvec, Q, REatt_T, v1,
                     Watt, out_ratt);
  hipLaunchKernelGGL(scores_kernel, dim3(512), dim3(512), 0, stream, X2,
                     rel_emb, ent_emb, r_space, e_space, mask, out_dist,
                     out_ent);
}